// Round 7
// baseline (773.693 us; speedup 1.0000x reference)
//
#include <hip/hip_runtime.h>

// Problem constants
#define NBANDS 64
#define LATENT 256
#define HIDDEN 512
#define GQ 8
#define KQ 1024
#define GD 32
#define NROWS 16000   // B*T = 16*1000

// d_out float offsets
#define OUT_BH   0
#define OUT_ZE   1024000
#define OUT_ZQ   5120000
#define OUT_IDX  9216000
#define OUT_LOSS 9344000

// ws float offsets (same footprint as rounds 1-6)
#define WS_H     0
#define WS_H2BF_F  0
#define WS_ZQB_F   4096000
#define WS_W1B_F   6144000
#define WS_W2B_F   6209536
#define WS_CN    8192000
#define WS_LOSS  8200192

typedef __attribute__((ext_vector_type(8))) short bf16x8;
typedef __attribute__((ext_vector_type(4))) float f32x4;

__device__ __forceinline__ unsigned short f2bf(float f) {
  unsigned u = __builtin_bit_cast(unsigned, f);
  unsigned r = u + 0x7FFFu + ((u >> 16) & 1u);   // RNE; inputs finite
  return (unsigned short)(r >> 16);
}

// ---------------------------------------------------------------------------
// fp32 GEMM, 128xBN tile, TMxTN microtile, BK=16, 256 threads. (unchanged)
// ---------------------------------------------------------------------------
template<int BN, int TM, int TN, bool RELU>
__global__ __launch_bounds__(256) void gemm_f32(
    const float* __restrict__ A, const float* __restrict__ B,
    const float* __restrict__ bias, float* __restrict__ C,
    int M, int N, int K) {
  constexpr int BM = 128;
  constexpr int BK = 16;
  constexpr int NTX = BN / TN;

  __shared__ float As[BK][BM + 8];
  __shared__ float Bs[BK][BN + 4];

  const int tid = threadIdx.x;
  const int tx = tid % NTX;
  const int ty = tid / NTX;
  const int row0 = blockIdx.y * BM;
  const int col0 = blockIdx.x * BN;

  const int arow = tid >> 1;
  const int akq  = (tid & 1) * 8;
  const int bkk = tid >> 4;
  const int bn  = (tid & 15) * (BN / 16);

  float acc[TM][TN] = {};

  for (int k0 = 0; k0 < K; k0 += BK) {
    float4 av0 = *reinterpret_cast<const float4*>(
        &A[(size_t)(row0 + arow) * K + k0 + akq]);
    float4 av1 = *reinterpret_cast<const float4*>(
        &A[(size_t)(row0 + arow) * K + k0 + akq + 4]);
    float4 bv0, bv1;
    bv0 = *reinterpret_cast<const float4*>(
        &B[(size_t)(k0 + bkk) * N + col0 + bn]);
    if (BN == 128)
      bv1 = *reinterpret_cast<const float4*>(
          &B[(size_t)(k0 + bkk) * N + col0 + bn + 4]);
    __syncthreads();
    As[akq + 0][arow] = av0.x; As[akq + 1][arow] = av0.y;
    As[akq + 2][arow] = av0.z; As[akq + 3][arow] = av0.w;
    As[akq + 4][arow] = av1.x; As[akq + 5][arow] = av1.y;
    As[akq + 6][arow] = av1.z; As[akq + 7][arow] = av1.w;
    *reinterpret_cast<float4*>(&Bs[bkk][bn]) = bv0;
    if (BN == 128)
      *reinterpret_cast<float4*>(&Bs[bkk][bn + 4]) = bv1;
    __syncthreads();

#pragma unroll
    for (int kk = 0; kk < BK; ++kk) {
      float a[TM], b[TN];
#pragma unroll
      for (int q = 0; q < TM / 4; ++q) {
        float4 v = *reinterpret_cast<const float4*>(&As[kk][ty * TM + q * 4]);
        a[q * 4 + 0] = v.x; a[q * 4 + 1] = v.y;
        a[q * 4 + 2] = v.z; a[q * 4 + 3] = v.w;
      }
#pragma unroll
      for (int q = 0; q < TN / 4; ++q) {
        float4 v = *reinterpret_cast<const float4*>(&Bs[kk][tx * TN + q * 4]);
        b[q * 4 + 0] = v.x; b[q * 4 + 1] = v.y;
        b[q * 4 + 2] = v.z; b[q * 4 + 3] = v.w;
      }
#pragma unroll
      for (int i = 0; i < TM; ++i)
#pragma unroll
        for (int j = 0; j < TN; ++j)
          acc[i][j] = fmaf(a[i], b[j], acc[i][j]);
    }
  }

  float bb[TN];
#pragma unroll
  for (int q = 0; q < TN / 4; ++q) {
    float4 v = *reinterpret_cast<const float4*>(&bias[col0 + tx * TN + q * 4]);
    bb[q * 4 + 0] = v.x; bb[q * 4 + 1] = v.y;
    bb[q * 4 + 2] = v.z; bb[q * 4 + 3] = v.w;
  }
#pragma unroll
  for (int i = 0; i < TM; ++i) {
    const int r = row0 + ty * TM + i;
#pragma unroll
    for (int q = 0; q < TN / 4; ++q) {
      float4 v;
      float* vp = &v.x;
#pragma unroll
      for (int j = 0; j < 4; ++j) {
        float t = acc[i][q * 4 + j] + bb[q * 4 + j];
        if (RELU) t = fmaxf(t, 0.0f);
        vp[j] = t;
      }
      *reinterpret_cast<float4*>(&C[(size_t)r * N + col0 + tx * TN + q * 4]) = v;
    }
  }
}

// ---------------------------------------------------------------------------
// bf16 MFMA GEMM (unchanged)
// ---------------------------------------------------------------------------
template<int WM, bool OUT_BF16>
__global__ __launch_bounds__(256) void gemm_bf16_mfma(
    const unsigned short* __restrict__ A, const unsigned short* __restrict__ B,
    const float* __restrict__ bias, void* __restrict__ Cout,
    int M, int N, int K) {
  constexpr int BM = 4 * WM;
  constexpr int MT = WM / 16;

  __shared__ unsigned short As[BM][40];
  __shared__ unsigned short Bs[64][40];

  const int tid  = threadIdx.x;
  const int wave = tid >> 6;
  const int lane = tid & 63;
  const int quad = lane >> 4;
  const int l16  = lane & 15;
  const int row0 = blockIdx.y * BM;
  const int col0 = blockIdx.x * 64;

  f32x4 acc[MT][4];
#pragma unroll
  for (int mt = 0; mt < MT; ++mt)
#pragma unroll
    for (int nt = 0; nt < 4; ++nt) acc[mt][nt] = (f32x4){0.f, 0.f, 0.f, 0.f};

  for (int k0 = 0; k0 < K; k0 += 32) {
    __syncthreads();
    if constexpr (BM == 128) {
      const int r = tid >> 1, seg = (tid & 1) * 16;
      const uint4* src = reinterpret_cast<const uint4*>(
          &A[(size_t)(row0 + r) * K + k0 + seg]);
      uint4* dst = reinterpret_cast<uint4*>(&As[r][seg]);
      dst[0] = src[0]; dst[1] = src[1];
    } else {
      const int r = tid >> 2, seg = (tid & 3) * 8;
      *reinterpret_cast<uint4*>(&As[r][seg]) =
          *reinterpret_cast<const uint4*>(&A[(size_t)(row0 + r) * K + k0 + seg]);
    }
    {
      const int kk = tid >> 3, n0 = (tid & 7) * 8;
      uint4 bv = *reinterpret_cast<const uint4*>(
          &B[(size_t)(k0 + kk) * N + col0 + n0]);
      unsigned short t[8];
      *reinterpret_cast<uint4*>(t) = bv;
#pragma unroll
      for (int j = 0; j < 8; ++j) Bs[n0 + j][kk] = t[j];
    }
    __syncthreads();

    bf16x8 af[MT], bf[4];
#pragma unroll
    for (int mt = 0; mt < MT; ++mt)
      af[mt] = *reinterpret_cast<const bf16x8*>(
          &As[wave * WM + mt * 16 + l16][quad * 8]);
#pragma unroll
    for (int nt = 0; nt < 4; ++nt)
      bf[nt] = *reinterpret_cast<const bf16x8*>(&Bs[nt * 16 + l16][quad * 8]);
#pragma unroll
    for (int mt = 0; mt < MT; ++mt)
#pragma unroll
      for (int nt = 0; nt < 4; ++nt)
        acc[mt][nt] = __builtin_amdgcn_mfma_f32_16x16x32_bf16(
            af[mt], bf[nt], acc[mt][nt], 0, 0, 0);
  }

#pragma unroll
  for (int mt = 0; mt < MT; ++mt)
#pragma unroll
    for (int nt = 0; nt < 4; ++nt) {
      const int col = col0 + nt * 16 + l16;
      const float bv = bias[col];
#pragma unroll
      for (int r = 0; r < 4; ++r) {
        const int grow = row0 + wave * WM + mt * 16 + quad * 4 + r;
        float v = acc[mt][nt][r] + bv;
        if constexpr (OUT_BF16) {
          v = fmaxf(v, 0.0f);
          ((unsigned short*)Cout)[(size_t)grow * N + col] = f2bf(v);
        } else {
          ((float*)Cout)[(size_t)grow * N + col] = v;
        }
      }
    }
}

// ---------------------------------------------------------------------------
__global__ void cn_kernel(const float* __restrict__ cb, float* __restrict__ cn,
                          float* __restrict__ loss_acc) {
  const int i = blockIdx.x * 256 + threadIdx.x;
  if (i == 0) loss_acc[0] = 0.0f;
  if (i < GQ * KQ) {
    const float* c = cb + (size_t)i * GD;
    float s = 0.0f;
#pragma unroll
    for (int d = 0; d < GD; ++d) s = fmaf(c[d], c[d], s);
    cn[i] = s;
  }
}

__global__ void wconv_kernel(const float* __restrict__ w1, const float* __restrict__ w2,
                             unsigned short* __restrict__ w1b,
                             unsigned short* __restrict__ w2b) {
  const int i = blockIdx.x * 256 + threadIdx.x;
  const int n1 = LATENT * HIDDEN;
  const int n2 = HIDDEN * NBANDS;
  if (i < n1) w1b[i] = f2bf(w1[i]);
  else if (i < n1 + n2) w2b[i - n1] = f2bf(w2[i - n1]);
}

// ---------------------------------------------------------------------------
// VQ round 7: 8 rows x 8 cw per thread (round-5 tile, no spills), but the
// B-operand (codebook) is read DIRECT FROM GLOBAL (L1-resident: 16 KB/chunk
// reused by all 256 threads) instead of LDS -> LDS pipe carries only the
// z-tile a-reads (64 b128/wave/chunk x 12cyc = 12.3k cyc < 16.4k VALU cyc
// per epoch => VALU-bound; was 1.5x LDS-oversubscribed).  a-reads are
// de-conflicted by ty-rotating the row iteration ((s+ty)&7): the 4 ty-groups
// per wave land on disjoint bank quads.  No cb staging => no per-chunk
// barriers (3 total).  Dot chain (d ascending, xyzw), per-thread ascending-k
// argmin, lexicographic merge: IDENTICAL to all passing rounds ->
// bit-identical distances -> identical argmin.
// ---------------------------------------------------------------------------
#define VQ_ROWS 128
#define VQ_CHUNK 128
#define VQ_NCHUNK (KQ / VQ_CHUNK)   // 8
#define ZPAD 36

__global__ __launch_bounds__(256) void vq_kernel(
    const float* __restrict__ z_e, const float* __restrict__ cb,
    const float* __restrict__ cn, float* __restrict__ z_q,
    unsigned short* __restrict__ zqb,
    float* __restrict__ idx_out, float* __restrict__ loss_acc) {
  const int g    = blockIdx.y;
  const int row0 = blockIdx.x * VQ_ROWS;
  const int tid  = threadIdx.x;
  const int tx   = tid & 15;    // codeword stripe (k % 16 == tx)
  const int ty   = tid >> 4;    // row octet: rows ty*8 .. ty*8+7

  __shared__ float z_lds[VQ_ROWS][ZPAD];   // 18432 B
  __shared__ float m_d[16][129];           //  8256 B
  __shared__ int   m_i[16][129];           //  8256 B
  __shared__ float red[VQ_ROWS];           //   512 B

  const float* cbg = cb + (size_t)g * KQ * GD;
  const float* cbt = cbg + (size_t)tx * GD;       // this thread's stripe base
  const float* cng = cn + (size_t)g * KQ;

  // stage z tile: thread t loads 16 floats of row (t>>1)
  {
    const int r   = tid >> 1;
    const int off = (tid & 1) << 4;
    const float4* src = reinterpret_cast<const float4*>(
        &z_e[(size_t)(row0 + r) * LATENT + g * GD + off]);
#pragma unroll
    for (int q = 0; q < 4; ++q)
      *reinterpret_cast<float4*>(&z_lds[r][off + q * 4]) = src[q];
  }
  __syncthreads();

  float best[8];
  int   bidx[8];
#pragma unroll
  for (int i = 0; i < 8; ++i) { best[i] = 3.0e38f; bidx[i] = 0; }

  for (int ch = 0; ch < VQ_NCHUNK; ++ch) {
    float acc[8][8];
#pragma unroll
    for (int i = 0; i < 8; ++i)
#pragma unroll
      for (int j = 0; j < 8; ++j) acc[i][j] = 0.0f;

    const float* cbc = cbt + (size_t)ch * VQ_CHUNK * GD;  // + ch*4096 floats

#pragma unroll 2
    for (int d0 = 0; d0 < GD; d0 += 4) {
      float4 a[8], b[8];
      // a from LDS, ty-rotated row order -> conflict-free across ty groups
#pragma unroll
      for (int s = 0; s < 8; ++s) {
        const int i = (s + ty) & 7;
        a[i] = *reinterpret_cast<const float4*>(&z_lds[ty * 8 + i][d0]);
      }
      // b direct from global (L1): cw k = ch*128 + j*16 + tx
#pragma unroll
      for (int j = 0; j < 8; ++j)
        b[j] = *reinterpret_cast<const float4*>(&cbc[j * 16 * GD + d0]);
#pragma unroll
      for (int i = 0; i < 8; ++i)
#pragma unroll
        for (int j = 0; j < 8; ++j) {
          float t = acc[i][j];
          t = fmaf(a[i].x, b[j].x, t);
          t = fmaf(a[i].y, b[j].y, t);
          t = fmaf(a[i].z, b[j].z, t);
          t = fmaf(a[i].w, b[j].w, t);
          acc[i][j] = t;
        }
    }

    // distances + running argmin (ascending k within thread)
#pragma unroll
    for (int j = 0; j < 8; ++j) {
      const int k = ch * VQ_CHUNK + j * 16 + tx;
      const float cnv = cng[k];
#pragma unroll
      for (int i = 0; i < 8; ++i) {
        const float dist = fmaf(-2.0f, acc[i][j], cnv);
        if (dist < best[i]) { best[i] = dist; bidx[i] = k; }
      }
    }
  }

  // merge 16 tx-partials per row
#pragma unroll
  for (int i = 0; i < 8; ++i) {
    m_d[tx][ty * 8 + i] = best[i];
    m_i[tx][ty * 8 + i] = bidx[i];
  }
  __syncthreads();

  float sse_part = 0.0f;
  if (tid < VQ_ROWS) {
    const int row = tid;
    float mb = m_d[0][row];
    int   mi = m_i[0][row];
#pragma unroll
    for (int t = 1; t < 16; ++t) {
      const float v = m_d[t][row];
      const int  ix = m_i[t][row];
      if (v < mb || (v == mb && ix < mi)) { mb = v; mi = ix; }
    }

    const float* c = cbg + (size_t)mi * GD;
    float cw[GD];
#pragma unroll
    for (int q = 0; q < 8; ++q) {
      float4 v = *reinterpret_cast<const float4*>(&c[q * 4]);
      cw[q * 4 + 0] = v.x; cw[q * 4 + 1] = v.y;
      cw[q * 4 + 2] = v.z; cw[q * 4 + 3] = v.w;
    }
    float sse = 0.0f;
#pragma unroll
    for (int d = 0; d < GD; ++d) {
      const float diff = cw[d] - z_lds[row][d];
      sse = fmaf(diff, diff, sse);
    }
    float4* zq = reinterpret_cast<float4*>(
        &z_q[(size_t)(row0 + row) * LATENT + g * GD]);
#pragma unroll
    for (int q = 0; q < 8; ++q)
      zq[q] = make_float4(cw[q * 4], cw[q * 4 + 1], cw[q * 4 + 2], cw[q * 4 + 3]);

    alignas(16) unsigned short zb[GD];
#pragma unroll
    for (int d = 0; d < GD; ++d) zb[d] = f2bf(cw[d]);
    uint4* dstb = reinterpret_cast<uint4*>(
        zqb + (size_t)(row0 + row) * LATENT + g * GD);
    const uint4* srcb = reinterpret_cast<const uint4*>(zb);
#pragma unroll
    for (int q = 0; q < 4; ++q) dstb[q] = srcb[q];

    idx_out[(size_t)(row0 + row) * GQ + g] = (float)mi;
    sse_part = sse;
  }

  // block SSE reduction, one atomic
  if (tid < VQ_ROWS) red[tid] = sse_part;
  __syncthreads();
  if (tid < 64) {
    float s = red[tid] + red[tid + 64];
#pragma unroll
    for (int off = 32; off > 0; off >>= 1)
      s += __shfl_down(s, off, 64);
    if (tid == 0) atomicAdd(loss_acc, s);
  }
}

__global__ void loss_kernel(const float* __restrict__ acc,
                            float* __restrict__ out) {
  out[0] = 0.5f * acc[0] / (float)((size_t)NROWS * GD);
}

// ---------------------------------------------------------------------------
extern "C" void kernel_launch(void* const* d_in, const int* in_sizes, int n_in,
                              void* d_out, int out_size, void* d_ws, size_t ws_size,
                              hipStream_t stream) {
  const float* bands  = (const float*)d_in[0];
  const float* enc_w1 = (const float*)d_in[1];
  const float* enc_b1 = (const float*)d_in[2];
  const float* enc_w2 = (const float*)d_in[3];
  const float* enc_b2 = (const float*)d_in[4];
  const float* cbooks = (const float*)d_in[5];
  const float* dec_w1 = (const float*)d_in[6];
  const float* dec_b1 = (const float*)d_in[7];
  const float* dec_w2 = (const float*)d_in[8];
  const float* dec_b2 = (const float*)d_in[9];

  float* out = (float*)d_out;
  float* ws  = (float*)d_ws;

  float* bands_hat = out + OUT_BH;
  float* z_e       = out + OUT_ZE;
  float* z_q       = out + OUT_ZQ;
  float* idx_f     = out + OUT_IDX;
  float* loss_out  = out + OUT_LOSS;

  float* H        = ws + WS_H;
  float* cn       = ws + WS_CN;
  float* loss_acc = ws + WS_LOSS;
  unsigned short* h2bf = (unsigned short*)(ws + WS_H2BF_F);
  unsigned short* zqb  = (unsigned short*)(ws + WS_ZQB_F);
  unsigned short* w1b  = (unsigned short*)(ws + WS_W1B_F);
  unsigned short* w2b  = (unsigned short*)(ws + WS_W2B_F);

  cn_kernel<<<dim3((GQ * KQ + 255) / 256), dim3(256), 0, stream>>>(cbooks, cn, loss_acc);

  // Encoder (fp32): H = relu(bands@W1+b1); z_e = H@W2+b2 (enc2 back to r5 cfg)
  gemm_f32<128, 8, 8, true ><<<dim3(HIDDEN / 128, NROWS / 128), dim3(256), 0, stream>>>(
      bands, enc_w1, enc_b1, H, NROWS, HIDDEN, NBANDS);
  gemm_f32<64, 4, 8, false><<<dim3(LATENT / 64, NROWS / 128), dim3(256), 0, stream>>>(
      H, enc_w2, enc_b2, z_e, NROWS, LATENT, HIDDEN);

  // Decoder weights -> bf16
  wconv_kernel<<<dim3((LATENT * HIDDEN + HIDDEN * NBANDS + 255) / 256), dim3(256), 0, stream>>>(
      dec_w1, dec_w2, w1b, w2b);

  // VQ (fp32 exact; also emits bf16 z_q)
  vq_kernel<<<dim3(NROWS / VQ_ROWS, GQ), dim3(256), 0, stream>>>(
      z_e, cbooks, cn, z_q, zqb, idx_f, loss_acc);

  // Decoder (bf16 MFMA)
  gemm_bf16_mfma<32, true ><<<dim3(HIDDEN / 64, NROWS / 128), dim3(256), 0, stream>>>(
      zqb, w1b, dec_b1, (void*)h2bf, NROWS, HIDDEN, LATENT);
  gemm_bf16_mfma<16, false><<<dim3(NBANDS / 64, NROWS / 64), dim3(256), 0, stream>>>(
      h2bf, w2b, dec_b2, (void*)bands_hat, NROWS, NBANDS, HIDDEN);

  loss_kernel<<<1, 1, 0, stream>>>(loss_acc, loss_out);
}

// Round 8
// 437.800 us; speedup vs baseline: 1.7672x; 1.7672x over previous
//
#include <hip/hip_runtime.h>

// Problem constants
#define NBANDS 64
#define LATENT 256
#define HIDDEN 512
#define GQ 8
#define KQ 1024
#define GD 32
#define NROWS 16000   // B*T = 16*1000

// d_out float offsets
#define OUT_BH   0
#define OUT_ZE   1024000
#define OUT_ZQ   5120000
#define OUT_IDX  9216000
#define OUT_LOSS 9344000

// ws float offsets (same footprint as rounds 1-7)
#define WS_H     0
#define WS_H2BF_F  0
#define WS_ZQB_F   4096000
#define WS_W1B_F   6144000
#define WS_W2B_F   6209536
#define WS_CN    8192000
#define WS_LOSS  8200192

typedef __attribute__((ext_vector_type(8))) short bf16x8;
typedef __attribute__((ext_vector_type(4))) float f32x4;

__device__ __forceinline__ unsigned short f2bf(float f) {
  unsigned u = __builtin_bit_cast(unsigned, f);
  unsigned r = u + 0x7FFFu + ((u >> 16) & 1u);   // RNE; inputs finite
  return (unsigned short)(r >> 16);
}

// ---------------------------------------------------------------------------
// fp32 GEMM, 128xBN tile, TMxTN microtile, BK=16, 256 threads. (unchanged)
// ---------------------------------------------------------------------------
template<int BN, int TM, int TN, bool RELU>
__global__ __launch_bounds__(256) void gemm_f32(
    const float* __restrict__ A, const float* __restrict__ B,
    const float* __restrict__ bias, float* __restrict__ C,
    int M, int N, int K) {
  constexpr int BM = 128;
  constexpr int BK = 16;
  constexpr int NTX = BN / TN;

  __shared__ float As[BK][BM + 8];
  __shared__ float Bs[BK][BN + 4];

  const int tid = threadIdx.x;
  const int tx = tid % NTX;
  const int ty = tid / NTX;
  const int row0 = blockIdx.y * BM;
  const int col0 = blockIdx.x * BN;

  const int arow = tid >> 1;
  const int akq  = (tid & 1) * 8;
  const int bkk = tid >> 4;
  const int bn  = (tid & 15) * (BN / 16);

  float acc[TM][TN] = {};

  for (int k0 = 0; k0 < K; k0 += BK) {
    float4 av0 = *reinterpret_cast<const float4*>(
        &A[(size_t)(row0 + arow) * K + k0 + akq]);
    float4 av1 = *reinterpret_cast<const float4*>(
        &A[(size_t)(row0 + arow) * K + k0 + akq + 4]);
    float4 bv0, bv1;
    bv0 = *reinterpret_cast<const float4*>(
        &B[(size_t)(k0 + bkk) * N + col0 + bn]);
    if (BN == 128)
      bv1 = *reinterpret_cast<const float4*>(
          &B[(size_t)(k0 + bkk) * N + col0 + bn + 4]);
    __syncthreads();
    As[akq + 0][arow] = av0.x; As[akq + 1][arow] = av0.y;
    As[akq + 2][arow] = av0.z; As[akq + 3][arow] = av0.w;
    As[akq + 4][arow] = av1.x; As[akq + 5][arow] = av1.y;
    As[akq + 6][arow] = av1.z; As[akq + 7][arow] = av1.w;
    *reinterpret_cast<float4*>(&Bs[bkk][bn]) = bv0;
    if (BN == 128)
      *reinterpret_cast<float4*>(&Bs[bkk][bn + 4]) = bv1;
    __syncthreads();

#pragma unroll
    for (int kk = 0; kk < BK; ++kk) {
      float a[TM], b[TN];
#pragma unroll
      for (int q = 0; q < TM / 4; ++q) {
        float4 v = *reinterpret_cast<const float4*>(&As[kk][ty * TM + q * 4]);
        a[q * 4 + 0] = v.x; a[q * 4 + 1] = v.y;
        a[q * 4 + 2] = v.z; a[q * 4 + 3] = v.w;
      }
#pragma unroll
      for (int q = 0; q < TN / 4; ++q) {
        float4 v = *reinterpret_cast<const float4*>(&Bs[kk][tx * TN + q * 4]);
        b[q * 4 + 0] = v.x; b[q * 4 + 1] = v.y;
        b[q * 4 + 2] = v.z; b[q * 4 + 3] = v.w;
      }
#pragma unroll
      for (int i = 0; i < TM; ++i)
#pragma unroll
        for (int j = 0; j < TN; ++j)
          acc[i][j] = fmaf(a[i], b[j], acc[i][j]);
    }
  }

  float bb[TN];
#pragma unroll
  for (int q = 0; q < TN / 4; ++q) {
    float4 v = *reinterpret_cast<const float4*>(&bias[col0 + tx * TN + q * 4]);
    bb[q * 4 + 0] = v.x; bb[q * 4 + 1] = v.y;
    bb[q * 4 + 2] = v.z; bb[q * 4 + 3] = v.w;
  }
#pragma unroll
  for (int i = 0; i < TM; ++i) {
    const int r = row0 + ty * TM + i;
#pragma unroll
    for (int q = 0; q < TN / 4; ++q) {
      float4 v;
      float* vp = &v.x;
#pragma unroll
      for (int j = 0; j < 4; ++j) {
        float t = acc[i][q * 4 + j] + bb[q * 4 + j];
        if (RELU) t = fmaxf(t, 0.0f);
        vp[j] = t;
      }
      *reinterpret_cast<float4*>(&C[(size_t)r * N + col0 + tx * TN + q * 4]) = v;
    }
  }
}

// ---------------------------------------------------------------------------
// bf16 MFMA GEMM (unchanged)
// ---------------------------------------------------------------------------
template<int WM, bool OUT_BF16>
__global__ __launch_bounds__(256) void gemm_bf16_mfma(
    const unsigned short* __restrict__ A, const unsigned short* __restrict__ B,
    const float* __restrict__ bias, void* __restrict__ Cout,
    int M, int N, int K) {
  constexpr int BM = 4 * WM;
  constexpr int MT = WM / 16;

  __shared__ unsigned short As[BM][40];
  __shared__ unsigned short Bs[64][40];

  const int tid  = threadIdx.x;
  const int wave = tid >> 6;
  const int lane = tid & 63;
  const int quad = lane >> 4;
  const int l16  = lane & 15;
  const int row0 = blockIdx.y * BM;
  const int col0 = blockIdx.x * 64;

  f32x4 acc[MT][4];
#pragma unroll
  for (int mt = 0; mt < MT; ++mt)
#pragma unroll
    for (int nt = 0; nt < 4; ++nt) acc[mt][nt] = (f32x4){0.f, 0.f, 0.f, 0.f};

  for (int k0 = 0; k0 < K; k0 += 32) {
    __syncthreads();
    if constexpr (BM == 128) {
      const int r = tid >> 1, seg = (tid & 1) * 16;
      const uint4* src = reinterpret_cast<const uint4*>(
          &A[(size_t)(row0 + r) * K + k0 + seg]);
      uint4* dst = reinterpret_cast<uint4*>(&As[r][seg]);
      dst[0] = src[0]; dst[1] = src[1];
    } else {
      const int r = tid >> 2, seg = (tid & 3) * 8;
      *reinterpret_cast<uint4*>(&As[r][seg]) =
          *reinterpret_cast<const uint4*>(&A[(size_t)(row0 + r) * K + k0 + seg]);
    }
    {
      const int kk = tid >> 3, n0 = (tid & 7) * 8;
      uint4 bv = *reinterpret_cast<const uint4*>(
          &B[(size_t)(k0 + kk) * N + col0 + n0]);
      unsigned short t[8];
      *reinterpret_cast<uint4*>(t) = bv;
#pragma unroll
      for (int j = 0; j < 8; ++j) Bs[n0 + j][kk] = t[j];
    }
    __syncthreads();

    bf16x8 af[MT], bf[4];
#pragma unroll
    for (int mt = 0; mt < MT; ++mt)
      af[mt] = *reinterpret_cast<const bf16x8*>(
          &As[wave * WM + mt * 16 + l16][quad * 8]);
#pragma unroll
    for (int nt = 0; nt < 4; ++nt)
      bf[nt] = *reinterpret_cast<const bf16x8*>(&Bs[nt * 16 + l16][quad * 8]);
#pragma unroll
    for (int mt = 0; mt < MT; ++mt)
#pragma unroll
      for (int nt = 0; nt < 4; ++nt)
        acc[mt][nt] = __builtin_amdgcn_mfma_f32_16x16x32_bf16(
            af[mt], bf[nt], acc[mt][nt], 0, 0, 0);
  }

#pragma unroll
  for (int mt = 0; mt < MT; ++mt)
#pragma unroll
    for (int nt = 0; nt < 4; ++nt) {
      const int col = col0 + nt * 16 + l16;
      const float bv = bias[col];
#pragma unroll
      for (int r = 0; r < 4; ++r) {
        const int grow = row0 + wave * WM + mt * 16 + quad * 4 + r;
        float v = acc[mt][nt][r] + bv;
        if constexpr (OUT_BF16) {
          v = fmaxf(v, 0.0f);
          ((unsigned short*)Cout)[(size_t)grow * N + col] = f2bf(v);
        } else {
          ((float*)Cout)[(size_t)grow * N + col] = v;
        }
      }
    }
}

// ---------------------------------------------------------------------------
__global__ void cn_kernel(const float* __restrict__ cb, float* __restrict__ cn,
                          float* __restrict__ loss_acc) {
  const int i = blockIdx.x * 256 + threadIdx.x;
  if (i == 0) loss_acc[0] = 0.0f;
  if (i < GQ * KQ) {
    const float* c = cb + (size_t)i * GD;
    float s = 0.0f;
#pragma unroll
    for (int d = 0; d < GD; ++d) s = fmaf(c[d], c[d], s);
    cn[i] = s;
  }
}

__global__ void wconv_kernel(const float* __restrict__ w1, const float* __restrict__ w2,
                             unsigned short* __restrict__ w1b,
                             unsigned short* __restrict__ w2b) {
  const int i = blockIdx.x * 256 + threadIdx.x;
  const int n1 = LATENT * HIDDEN;
  const int n2 = HIDDEN * NBANDS;
  if (i < n1) w1b[i] = f2bf(w1[i]);
  else if (i < n1 + n2) w2b[i - n1] = f2bf(w2[i - n1]);
}

// ---------------------------------------------------------------------------
// VQ round 8: round-7 structure (B direct from global/L1, LDS only for the
// z-tile) with the spill bug excised:
//   * a[s] statically indexed (r7's (s+ty)&7 rotation made a[] dynamically
//     indexed -> compiler scratch -> 200 MB spill traffic, the r7 regression)
//   * 4-way a-read bank conflict fixed by XOR column swizzle instead:
//     z_lds[r][c ^ key(r)], key(r)=((r>>3)&3)<<2.  Within a wave the 4
//     ty-groups (r>>3 == ty) get keys {0,4,8,12} -> b128 reads land on 4
//     disjoint bank quads -> conflict-free; key is a per-thread constant so
//     all indices stay compile-time-affine (registers, no scratch).
// Dot chain (d ascending, xyzw), per-thread ascending-k argmin,
// lexicographic merge: IDENTICAL to all passing rounds -> bit-identical
// distances -> identical argmin.
// ---------------------------------------------------------------------------
#define VQ_ROWS 128
#define VQ_CHUNK 128
#define VQ_NCHUNK (KQ / VQ_CHUNK)   // 8
#define ZPAD 36

__global__ __launch_bounds__(256) void vq_kernel(
    const float* __restrict__ z_e, const float* __restrict__ cb,
    const float* __restrict__ cn, float* __restrict__ z_q,
    unsigned short* __restrict__ zqb,
    float* __restrict__ idx_out, float* __restrict__ loss_acc) {
  const int g    = blockIdx.y;
  const int row0 = blockIdx.x * VQ_ROWS;
  const int tid  = threadIdx.x;
  const int tx   = tid & 15;    // codeword stripe (k % 16 == tx)
  const int ty   = tid >> 4;    // row octet: rows ty*8 .. ty*8+7

  __shared__ float z_lds[VQ_ROWS][ZPAD];   // 18432 B (XOR-swizzled columns)
  __shared__ float m_d[16][129];           //  8256 B
  __shared__ int   m_i[16][129];           //  8256 B
  __shared__ float red[VQ_ROWS];           //   512 B

  const float* cbg = cb + (size_t)g * KQ * GD;
  const float* cbt = cbg + (size_t)tx * GD;       // this thread's stripe base
  const float* cng = cn + (size_t)g * KQ;

  // stage z tile (swizzled): thread t loads 16 floats of row (t>>1)
  {
    const int r   = tid >> 1;
    const int off = (tid & 1) << 4;
    const int key = ((r >> 3) & 3) << 2;
    const float4* src = reinterpret_cast<const float4*>(
        &z_e[(size_t)(row0 + r) * LATENT + g * GD + off]);
#pragma unroll
    for (int q = 0; q < 4; ++q)
      *reinterpret_cast<float4*>(&z_lds[r][(off + q * 4) ^ key]) = src[q];
  }
  __syncthreads();

  const int akey = (ty & 3) << 2;   // == key(row) for rows ty*8..ty*8+7

  float best[8];
  int   bidx[8];
#pragma unroll
  for (int i = 0; i < 8; ++i) { best[i] = 3.0e38f; bidx[i] = 0; }

  for (int ch = 0; ch < VQ_NCHUNK; ++ch) {
    float acc[8][8];
#pragma unroll
    for (int i = 0; i < 8; ++i)
#pragma unroll
      for (int j = 0; j < 8; ++j) acc[i][j] = 0.0f;

    const float* cbc = cbt + (size_t)ch * VQ_CHUNK * GD;  // + ch*4096 floats

#pragma unroll 2
    for (int d0 = 0; d0 < GD; d0 += 4) {
      float4 a[8], b[8];
      // a from LDS (swizzled col) — static indices, conflict-free
#pragma unroll
      for (int s = 0; s < 8; ++s)
        a[s] = *reinterpret_cast<const float4*>(&z_lds[ty * 8 + s][d0 ^ akey]);
      // b direct from global (L1): cw k = ch*128 + j*16 + tx
#pragma unroll
      for (int j = 0; j < 8; ++j)
        b[j] = *reinterpret_cast<const float4*>(&cbc[j * 16 * GD + d0]);
#pragma unroll
      for (int i = 0; i < 8; ++i)
#pragma unroll
        for (int j = 0; j < 8; ++j) {
          float t = acc[i][j];
          t = fmaf(a[i].x, b[j].x, t);
          t = fmaf(a[i].y, b[j].y, t);
          t = fmaf(a[i].z, b[j].z, t);
          t = fmaf(a[i].w, b[j].w, t);
          acc[i][j] = t;
        }
    }

    // distances + running argmin (ascending k within thread)
#pragma unroll
    for (int j = 0; j < 8; ++j) {
      const int k = ch * VQ_CHUNK + j * 16 + tx;
      const float cnv = cng[k];
#pragma unroll
      for (int i = 0; i < 8; ++i) {
        const float dist = fmaf(-2.0f, acc[i][j], cnv);
        if (dist < best[i]) { best[i] = dist; bidx[i] = k; }
      }
    }
  }

  // merge 16 tx-partials per row
#pragma unroll
  for (int i = 0; i < 8; ++i) {
    m_d[tx][ty * 8 + i] = best[i];
    m_i[tx][ty * 8 + i] = bidx[i];
  }
  __syncthreads();

  float sse_part = 0.0f;
  if (tid < VQ_ROWS) {
    const int row = tid;
    const int rkey = ((row >> 3) & 3) << 2;
    float mb = m_d[0][row];
    int   mi = m_i[0][row];
#pragma unroll
    for (int t = 1; t < 16; ++t) {
      const float v = m_d[t][row];
      const int  ix = m_i[t][row];
      if (v < mb || (v == mb && ix < mi)) { mb = v; mi = ix; }
    }

    const float* c = cbg + (size_t)mi * GD;
    float cw[GD];
#pragma unroll
    for (int q = 0; q < 8; ++q) {
      float4 v = *reinterpret_cast<const float4*>(&c[q * 4]);
      cw[q * 4 + 0] = v.x; cw[q * 4 + 1] = v.y;
      cw[q * 4 + 2] = v.z; cw[q * 4 + 3] = v.w;
    }
    float sse = 0.0f;
#pragma unroll
    for (int d = 0; d < GD; ++d) {
      const float diff = cw[d] - z_lds[row][d ^ rkey];
      sse = fmaf(diff, diff, sse);
    }
    float4* zq = reinterpret_cast<float4*>(
        &z_q[(size_t)(row0 + row) * LATENT + g * GD]);
#pragma unroll
    for (int q = 0; q < 8; ++q)
      zq[q] = make_float4(cw[q * 4], cw[q * 4 + 1], cw[q * 4 + 2], cw[q * 4 + 3]);

    alignas(16) unsigned short zb[GD];
#pragma unroll
    for (int d = 0; d < GD; ++d) zb[d] = f2bf(cw[d]);
    uint4* dstb = reinterpret_cast<uint4*>(
        zqb + (size_t)(row0 + row) * LATENT + g * GD);
    const uint4* srcb = reinterpret_cast<const uint4*>(zb);
#pragma unroll
    for (int q = 0; q < 4; ++q) dstb[q] = srcb[q];

    idx_out[(size_t)(row0 + row) * GQ + g] = (float)mi;
    sse_part = sse;
  }

  // block SSE reduction, one atomic
  if (tid < VQ_ROWS) red[tid] = sse_part;
  __syncthreads();
  if (tid < 64) {
    float s = red[tid] + red[tid + 64];
#pragma unroll
    for (int off = 32; off > 0; off >>= 1)
      s += __shfl_down(s, off, 64);
    if (tid == 0) atomicAdd(loss_acc, s);
  }
}

__global__ void loss_kernel(const float* __restrict__ acc,
                            float* __restrict__ out) {
  out[0] = 0.5f * acc[0] / (float)((size_t)NROWS * GD);
}

// ---------------------------------------------------------------------------
extern "C" void kernel_launch(void* const* d_in, const int* in_sizes, int n_in,
                              void* d_out, int out_size, void* d_ws, size_t ws_size,
                              hipStream_t stream) {
  const float* bands  = (const float*)d_in[0];
  const float* enc_w1 = (const float*)d_in[1];
  const float* enc_b1 = (const float*)d_in[2];
  const float* enc_w2 = (const float*)d_in[3];
  const float* enc_b2 = (const float*)d_in[4];
  const float* cbooks = (const float*)d_in[5];
  const float* dec_w1 = (const float*)d_in[6];
  const float* dec_b1 = (const float*)d_in[7];
  const float* dec_w2 = (const float*)d_in[8];
  const float* dec_b2 = (const float*)d_in[9];

  float* out = (float*)d_out;
  float* ws  = (float*)d_ws;

  float* bands_hat = out + OUT_BH;
  float* z_e       = out + OUT_ZE;
  float* z_q       = out + OUT_ZQ;
  float* idx_f     = out + OUT_IDX;
  float* loss_out  = out + OUT_LOSS;

  float* H        = ws + WS_H;
  float* cn       = ws + WS_CN;
  float* loss_acc = ws + WS_LOSS;
  unsigned short* h2bf = (unsigned short*)(ws + WS_H2BF_F);
  unsigned short* zqb  = (unsigned short*)(ws + WS_ZQB_F);
  unsigned short* w1b  = (unsigned short*)(ws + WS_W1B_F);
  unsigned short* w2b  = (unsigned short*)(ws + WS_W2B_F);

  cn_kernel<<<dim3((GQ * KQ + 255) / 256), dim3(256), 0, stream>>>(cbooks, cn, loss_acc);

  // Encoder (fp32): H = relu(bands@W1+b1); z_e = H@W2+b2
  gemm_f32<128, 8, 8, true ><<<dim3(HIDDEN / 128, NROWS / 128), dim3(256), 0, stream>>>(
      bands, enc_w1, enc_b1, H, NROWS, HIDDEN, NBANDS);
  gemm_f32<64, 4, 8, false><<<dim3(LATENT / 64, NROWS / 128), dim3(256), 0, stream>>>(
      H, enc_w2, enc_b2, z_e, NROWS, LATENT, HIDDEN);

  // Decoder weights -> bf16
  wconv_kernel<<<dim3((LATENT * HIDDEN + HIDDEN * NBANDS + 255) / 256), dim3(256), 0, stream>>>(
      dec_w1, dec_w2, w1b, w2b);

  // VQ (fp32 exact; also emits bf16 z_q)
  vq_kernel<<<dim3(NROWS / VQ_ROWS, GQ), dim3(256), 0, stream>>>(
      z_e, cbooks, cn, z_q, zqb, idx_f, loss_acc);

  // Decoder (bf16 MFMA)
  gemm_bf16_mfma<32, true ><<<dim3(HIDDEN / 64, NROWS / 128), dim3(256), 0, stream>>>(
      zqb, w1b, dec_b1, (void*)h2bf, NROWS, HIDDEN, LATENT);
  gemm_bf16_mfma<16, false><<<dim3(NBANDS / 64, NROWS / 64), dim3(256), 0, stream>>>(
      h2bf, w2b, dec_b2, (void*)bands_hat, NROWS, NBANDS, HIDDEN);

  loss_kernel<<<1, 1, 0, stream>>>(loss_acc, loss_out);
}

// Round 9
// 321.404 us; speedup vs baseline: 2.4072x; 1.3621x over previous
//
#include <hip/hip_runtime.h>

// Problem constants
#define NBANDS 64
#define LATENT 256
#define HIDDEN 512
#define GQ 8
#define KQ 1024
#define GD 32
#define NROWS 16000   // B*T = 16*1000

// d_out float offsets
#define OUT_BH   0
#define OUT_ZE   1024000
#define OUT_ZQ   5120000
#define OUT_IDX  9216000
#define OUT_LOSS 9344000

// ws float offsets (same footprint as rounds 1-8)
#define WS_H     0
#define WS_H2BF_F  0
#define WS_ZQB_F   4096000
#define WS_W1B_F   6144000
#define WS_W2B_F   6209536
#define WS_CN    8192000
#define WS_LOSS  8200192

typedef __attribute__((ext_vector_type(8))) short bf16x8;
typedef __attribute__((ext_vector_type(4))) float f32x4;

__device__ __forceinline__ unsigned short f2bf(float f) {
  unsigned u = __builtin_bit_cast(unsigned, f);
  unsigned r = u + 0x7FFFu + ((u >> 16) & 1u);   // RNE; inputs finite
  return (unsigned short)(r >> 16);
}

// async 16B global->LDS DMA (gfx950; LDS dst must be wave-uniform base + lane*16)
__device__ __forceinline__ void g2l16(const float* g, float* l) {
  __builtin_amdgcn_global_load_lds(
      (const __attribute__((address_space(1))) unsigned int*)g,
      (__attribute__((address_space(3))) unsigned int*)l, 16, 0, 0);
}

// ---------------------------------------------------------------------------
// fp32 GEMM, 128xBN tile, TMxTN microtile, BK=16, 256 threads. (unchanged)
// ---------------------------------------------------------------------------
template<int BN, int TM, int TN, bool RELU>
__global__ __launch_bounds__(256) void gemm_f32(
    const float* __restrict__ A, const float* __restrict__ B,
    const float* __restrict__ bias, float* __restrict__ C,
    int M, int N, int K) {
  constexpr int BM = 128;
  constexpr int BK = 16;
  constexpr int NTX = BN / TN;

  __shared__ float As[BK][BM + 8];
  __shared__ float Bs[BK][BN + 4];

  const int tid = threadIdx.x;
  const int tx = tid % NTX;
  const int ty = tid / NTX;
  const int row0 = blockIdx.y * BM;
  const int col0 = blockIdx.x * BN;

  const int arow = tid >> 1;
  const int akq  = (tid & 1) * 8;
  const int bkk = tid >> 4;
  const int bn  = (tid & 15) * (BN / 16);

  float acc[TM][TN] = {};

  for (int k0 = 0; k0 < K; k0 += BK) {
    float4 av0 = *reinterpret_cast<const float4*>(
        &A[(size_t)(row0 + arow) * K + k0 + akq]);
    float4 av1 = *reinterpret_cast<const float4*>(
        &A[(size_t)(row0 + arow) * K + k0 + akq + 4]);
    float4 bv0, bv1;
    bv0 = *reinterpret_cast<const float4*>(
        &B[(size_t)(k0 + bkk) * N + col0 + bn]);
    if (BN == 128)
      bv1 = *reinterpret_cast<const float4*>(
          &B[(size_t)(k0 + bkk) * N + col0 + bn + 4]);
    __syncthreads();
    As[akq + 0][arow] = av0.x; As[akq + 1][arow] = av0.y;
    As[akq + 2][arow] = av0.z; As[akq + 3][arow] = av0.w;
    As[akq + 4][arow] = av1.x; As[akq + 5][arow] = av1.y;
    As[akq + 6][arow] = av1.z; As[akq + 7][arow] = av1.w;
    *reinterpret_cast<float4*>(&Bs[bkk][bn]) = bv0;
    if (BN == 128)
      *reinterpret_cast<float4*>(&Bs[bkk][bn + 4]) = bv1;
    __syncthreads();

#pragma unroll
    for (int kk = 0; kk < BK; ++kk) {
      float a[TM], b[TN];
#pragma unroll
      for (int q = 0; q < TM / 4; ++q) {
        float4 v = *reinterpret_cast<const float4*>(&As[kk][ty * TM + q * 4]);
        a[q * 4 + 0] = v.x; a[q * 4 + 1] = v.y;
        a[q * 4 + 2] = v.z; a[q * 4 + 3] = v.w;
      }
#pragma unroll
      for (int q = 0; q < TN / 4; ++q) {
        float4 v = *reinterpret_cast<const float4*>(&Bs[kk][tx * TN + q * 4]);
        b[q * 4 + 0] = v.x; b[q * 4 + 1] = v.y;
        b[q * 4 + 2] = v.z; b[q * 4 + 3] = v.w;
      }
#pragma unroll
      for (int i = 0; i < TM; ++i)
#pragma unroll
        for (int j = 0; j < TN; ++j)
          acc[i][j] = fmaf(a[i], b[j], acc[i][j]);
    }
  }

  float bb[TN];
#pragma unroll
  for (int q = 0; q < TN / 4; ++q) {
    float4 v = *reinterpret_cast<const float4*>(&bias[col0 + tx * TN + q * 4]);
    bb[q * 4 + 0] = v.x; bb[q * 4 + 1] = v.y;
    bb[q * 4 + 2] = v.z; bb[q * 4 + 3] = v.w;
  }
#pragma unroll
  for (int i = 0; i < TM; ++i) {
    const int r = row0 + ty * TM + i;
#pragma unroll
    for (int q = 0; q < TN / 4; ++q) {
      float4 v;
      float* vp = &v.x;
#pragma unroll
      for (int j = 0; j < 4; ++j) {
        float t = acc[i][q * 4 + j] + bb[q * 4 + j];
        if (RELU) t = fmaxf(t, 0.0f);
        vp[j] = t;
      }
      *reinterpret_cast<float4*>(&C[(size_t)r * N + col0 + tx * TN + q * 4]) = v;
    }
  }
}

// ---------------------------------------------------------------------------
// bf16 MFMA GEMM (unchanged)
// ---------------------------------------------------------------------------
template<int WM, bool OUT_BF16>
__global__ __launch_bounds__(256) void gemm_bf16_mfma(
    const unsigned short* __restrict__ A, const unsigned short* __restrict__ B,
    const float* __restrict__ bias, void* __restrict__ Cout,
    int M, int N, int K) {
  constexpr int BM = 4 * WM;
  constexpr int MT = WM / 16;

  __shared__ unsigned short As[BM][40];
  __shared__ unsigned short Bs[64][40];

  const int tid  = threadIdx.x;
  const int wave = tid >> 6;
  const int lane = tid & 63;
  const int quad = lane >> 4;
  const int l16  = lane & 15;
  const int row0 = blockIdx.y * BM;
  const int col0 = blockIdx.x * 64;

  f32x4 acc[MT][4];
#pragma unroll
  for (int mt = 0; mt < MT; ++mt)
#pragma unroll
    for (int nt = 0; nt < 4; ++nt) acc[mt][nt] = (f32x4){0.f, 0.f, 0.f, 0.f};

  for (int k0 = 0; k0 < K; k0 += 32) {
    __syncthreads();
    if constexpr (BM == 128) {
      const int r = tid >> 1, seg = (tid & 1) * 16;
      const uint4* src = reinterpret_cast<const uint4*>(
          &A[(size_t)(row0 + r) * K + k0 + seg]);
      uint4* dst = reinterpret_cast<uint4*>(&As[r][seg]);
      dst[0] = src[0]; dst[1] = src[1];
    } else {
      const int r = tid >> 2, seg = (tid & 3) * 8;
      *reinterpret_cast<uint4*>(&As[r][seg]) =
          *reinterpret_cast<const uint4*>(&A[(size_t)(row0 + r) * K + k0 + seg]);
    }
    {
      const int kk = tid >> 3, n0 = (tid & 7) * 8;
      uint4 bv = *reinterpret_cast<const uint4*>(
          &B[(size_t)(k0 + kk) * N + col0 + n0]);
      unsigned short t[8];
      *reinterpret_cast<uint4*>(t) = bv;
#pragma unroll
      for (int j = 0; j < 8; ++j) Bs[n0 + j][kk] = t[j];
    }
    __syncthreads();

    bf16x8 af[MT], bf[4];
#pragma unroll
    for (int mt = 0; mt < MT; ++mt)
      af[mt] = *reinterpret_cast<const bf16x8*>(
          &As[wave * WM + mt * 16 + l16][quad * 8]);
#pragma unroll
    for (int nt = 0; nt < 4; ++nt)
      bf[nt] = *reinterpret_cast<const bf16x8*>(&Bs[nt * 16 + l16][quad * 8]);
#pragma unroll
    for (int mt = 0; mt < MT; ++mt)
#pragma unroll
      for (int nt = 0; nt < 4; ++nt)
        acc[mt][nt] = __builtin_amdgcn_mfma_f32_16x16x32_bf16(
            af[mt], bf[nt], acc[mt][nt], 0, 0, 0);
  }

#pragma unroll
  for (int mt = 0; mt < MT; ++mt)
#pragma unroll
    for (int nt = 0; nt < 4; ++nt) {
      const int col = col0 + nt * 16 + l16;
      const float bv = bias[col];
#pragma unroll
      for (int r = 0; r < 4; ++r) {
        const int grow = row0 + wave * WM + mt * 16 + quad * 4 + r;
        float v = acc[mt][nt][r] + bv;
        if constexpr (OUT_BF16) {
          v = fmaxf(v, 0.0f);
          ((unsigned short*)Cout)[(size_t)grow * N + col] = f2bf(v);
        } else {
          ((float*)Cout)[(size_t)grow * N + col] = v;
        }
      }
    }
}

// ---------------------------------------------------------------------------
__global__ void cn_kernel(const float* __restrict__ cb, float* __restrict__ cn,
                          float* __restrict__ loss_acc) {
  const int i = blockIdx.x * 256 + threadIdx.x;
  if (i == 0) loss_acc[0] = 0.0f;
  if (i < GQ * KQ) {
    const float* c = cb + (size_t)i * GD;
    float s = 0.0f;
#pragma unroll
    for (int d = 0; d < GD; ++d) s = fmaf(c[d], c[d], s);
    cn[i] = s;
  }
}

__global__ void wconv_kernel(const float* __restrict__ w1, const float* __restrict__ w2,
                             unsigned short* __restrict__ w1b,
                             unsigned short* __restrict__ w2b) {
  const int i = blockIdx.x * 256 + threadIdx.x;
  const int n1 = LATENT * HIDDEN;
  const int n2 = HIDDEN * NBANDS;
  if (i < n1) w1b[i] = f2bf(w1[i]);
  else if (i < n1 + n2) w2b[i - n1] = f2bf(w2[i - n1]);
}

// ---------------------------------------------------------------------------
// VQ round 9: round-5 LDS-B structure + ASYNC DOUBLE-BUFFERED cb staging via
// global_load_lds(16B).  DMA forces contiguous LDS placement (no padding), so
// bank conflicts are broken by permuting 16B quads at STAGE time through the
// per-lane GLOBAL source address:  slot(r,q) = r*8 + (q ^ (r&7)); compute
// reads with the inverse swizzle ((d0>>2) ^ (tx&7), thread-constant key,
// compile-time-affine -> registers, no scratch).  16 lanes -> 8 bank-quads
// x2 = 2-way = free.  Prefetch: barrier drains DMA(ch) (issued one full
// chunk earlier), then kick DMA(ch+1), then compute(ch) -> staging latency
// hidden, staging VALU ~ 4 DMA instr/thread/chunk.
// Data values, d-ascending dot order, fmaf(-2,dot,cn), per-thread
// ascending-k argmin, lexicographic merge: IDENTICAL to all passing rounds
// -> bit-identical distances -> identical argmin.
// LDS: z 18432 B + cb dbuf 32768 B = 51200 B (merge/red overlay cb region).
// ---------------------------------------------------------------------------
#define VQ_ROWS 128
#define VQ_CHUNK 128
#define VQ_NCHUNK (KQ / VQ_CHUNK)   // 8
#define ZPAD 36

__global__ __launch_bounds__(256) void vq_kernel(
    const float* __restrict__ z_e, const float* __restrict__ cb,
    const float* __restrict__ cn, float* __restrict__ z_q,
    unsigned short* __restrict__ zqb,
    float* __restrict__ idx_out, float* __restrict__ loss_acc) {
  const int g    = blockIdx.y;
  const int row0 = blockIdx.x * VQ_ROWS;
  const int tid  = threadIdx.x;
  const int tx   = tid & 15;    // codeword stripe (k % 16 == tx)
  const int ty   = tid >> 4;    // row octet: rows ty*8 .. ty*8+7

  __shared__ float smem[VQ_ROWS * ZPAD + 2 * VQ_CHUNK * GD];  // 51200 B
  float* zs  = smem;                       // [128][36], XOR col swizzle
  float* cbF = smem + VQ_ROWS * ZPAD;      // 2 x 4096 floats, DMA slots

  const float* cbg = cb + (size_t)g * KQ * GD;
  const float* cng = cn + (size_t)g * KQ;

  // ---- kick DMA for chunk 0 ----
  {
    const float* src = cbg;
    float* dst = cbF;
#pragma unroll
    for (int q4 = 0; q4 < 4; ++q4) {
      const int s = q4 * 256 + tid;
      const int r = s >> 3;
      const int q = (s & 7) ^ (r & 7);
      g2l16(src + r * GD + q * 4, dst + s * 4);
    }
  }

  // ---- stage z tile (swizzled cols): thread t loads 16 floats of row t>>1 ----
  {
    const int r   = tid >> 1;
    const int off = (tid & 1) << 4;
    const int key = ((r >> 3) & 3) << 2;
    const float4* src = reinterpret_cast<const float4*>(
        &z_e[(size_t)(row0 + r) * LATENT + g * GD + off]);
#pragma unroll
    for (int q = 0; q < 4; ++q)
      *reinterpret_cast<float4*>(&zs[r * ZPAD + ((off + q * 4) ^ key)]) = src[q];
  }

  const int akey = (ty & 3) << 2;   // z-read key for rows ty*8..ty*8+7
  const int bkey = tx & 7;          // cb quad-swizzle key (r&7 == tx&7)

  float best[8];
  int   bidx[8];
#pragma unroll
  for (int i = 0; i < 8; ++i) { best[i] = 3.0e38f; bidx[i] = 0; }

  for (int ch = 0; ch < VQ_NCHUNK; ++ch) {
    __syncthreads();   // drains DMA(ch) + joins compute(ch-1) (+ z stage)

    // prefetch chunk ch+1 into the other buffer (async; drained next barrier)
    if (ch + 1 < VQ_NCHUNK) {
      const float* src = cbg + (size_t)(ch + 1) * VQ_CHUNK * GD;
      float* dst = cbF + ((ch + 1) & 1) * (VQ_CHUNK * GD);
#pragma unroll
      for (int q4 = 0; q4 < 4; ++q4) {
        const int s = q4 * 256 + tid;
        const int r = s >> 3;
        const int q = (s & 7) ^ (r & 7);
        g2l16(src + r * GD + q * 4, dst + s * 4);
      }
    }

    const float* cbuf = cbF + (ch & 1) * (VQ_CHUNK * GD);

    float acc[8][8];
#pragma unroll
    for (int i = 0; i < 8; ++i)
#pragma unroll
      for (int j = 0; j < 8; ++j) acc[i][j] = 0.0f;

#pragma unroll 2
    for (int d0 = 0; d0 < GD; d0 += 4) {
      float4 a[8], b[8];
#pragma unroll
      for (int s = 0; s < 8; ++s)
        a[s] = *reinterpret_cast<const float4*>(
            &zs[(ty * 8 + s) * ZPAD + (d0 ^ akey)]);
      const int bq = ((d0 >> 2) ^ bkey) << 2;
#pragma unroll
      for (int j = 0; j < 8; ++j)
        b[j] = *reinterpret_cast<const float4*>(
            &cbuf[(j * 16 + tx) * GD + bq]);
#pragma unroll
      for (int i = 0; i < 8; ++i)
#pragma unroll
        for (int j = 0; j < 8; ++j) {
          float t = acc[i][j];
          t = fmaf(a[i].x, b[j].x, t);
          t = fmaf(a[i].y, b[j].y, t);
          t = fmaf(a[i].z, b[j].z, t);
          t = fmaf(a[i].w, b[j].w, t);
          acc[i][j] = t;
        }
    }

    // distances + running argmin (ascending k within thread)
#pragma unroll
    for (int j = 0; j < 8; ++j) {
      const int k = ch * VQ_CHUNK + j * 16 + tx;
      const float cnv = cng[k];
#pragma unroll
      for (int i = 0; i < 8; ++i) {
        const float dist = fmaf(-2.0f, acc[i][j], cnv);
        if (dist < best[i]) { best[i] = dist; bidx[i] = k; }
      }
    }
  }

  // ---- merge 16 tx-partials per row (overlay onto cb buffers) ----
  __syncthreads();   // all chunk compute done before overlay writes
  float* m_d = cbF;                                  // [16][129] floats
  int*   m_i = reinterpret_cast<int*>(cbF + 16 * 129);
  float* red = cbF + 2 * 16 * 129 + 32;              // 128 floats
#pragma unroll
  for (int i = 0; i < 8; ++i) {
    m_d[tx * 129 + ty * 8 + i] = best[i];
    m_i[tx * 129 + ty * 8 + i] = bidx[i];
  }
  __syncthreads();

  float sse_part = 0.0f;
  if (tid < VQ_ROWS) {
    const int row = tid;
    const int rkey = ((row >> 3) & 3) << 2;
    float mb = m_d[row];
    int   mi = m_i[row];
#pragma unroll
    for (int t = 1; t < 16; ++t) {
      const float v = m_d[t * 129 + row];
      const int  ix = m_i[t * 129 + row];
      if (v < mb || (v == mb && ix < mi)) { mb = v; mi = ix; }
    }

    const float* c = cbg + (size_t)mi * GD;
    float cw[GD];
#pragma unroll
    for (int q = 0; q < 8; ++q) {
      float4 v = *reinterpret_cast<const float4*>(&c[q * 4]);
      cw[q * 4 + 0] = v.x; cw[q * 4 + 1] = v.y;
      cw[q * 4 + 2] = v.z; cw[q * 4 + 3] = v.w;
    }
    float sse = 0.0f;
#pragma unroll
    for (int d = 0; d < GD; ++d) {
      const float diff = cw[d] - zs[row * ZPAD + (d ^ rkey)];
      sse = fmaf(diff, diff, sse);
    }
    float4* zq = reinterpret_cast<float4*>(
        &z_q[(size_t)(row0 + row) * LATENT + g * GD]);
#pragma unroll
    for (int q = 0; q < 8; ++q)
      zq[q] = make_float4(cw[q * 4], cw[q * 4 + 1], cw[q * 4 + 2], cw[q * 4 + 3]);

    alignas(16) unsigned short zb[GD];
#pragma unroll
    for (int d = 0; d < GD; ++d) zb[d] = f2bf(cw[d]);
    uint4* dstb = reinterpret_cast<uint4*>(
        zqb + (size_t)(row0 + row) * LATENT + g * GD);
    const uint4* srcb = reinterpret_cast<const uint4*>(zb);
#pragma unroll
    for (int q = 0; q < 4; ++q) dstb[q] = srcb[q];

    idx_out[(size_t)(row0 + row) * GQ + g] = (float)mi;
    sse_part = sse;
  }

  // block SSE reduction, one atomic (red lives past the merge arrays)
  if (tid < VQ_ROWS) red[tid] = sse_part;
  __syncthreads();
  if (tid < 64) {
    float s = red[tid] + red[tid + 64];
#pragma unroll
    for (int off = 32; off > 0; off >>= 1)
      s += __shfl_down(s, off, 64);
    if (tid == 0) atomicAdd(loss_acc, s);
  }
}

__global__ void loss_kernel(const float* __restrict__ acc,
                            float* __restrict__ out) {
  out[0] = 0.5f * acc[0] / (float)((size_t)NROWS * GD);
}

// ---------------------------------------------------------------------------
extern "C" void kernel_launch(void* const* d_in, const int* in_sizes, int n_in,
                              void* d_out, int out_size, void* d_ws, size_t ws_size,
                              hipStream_t stream) {
  const float* bands  = (const float*)d_in[0];
  const float* enc_w1 = (const float*)d_in[1];
  const float* enc_b1 = (const float*)d_in[2];
  const float* enc_w2 = (const float*)d_in[3];
  const float* enc_b2 = (const float*)d_in[4];
  const float* cbooks = (const float*)d_in[5];
  const float* dec_w1 = (const float*)d_in[6];
  const float* dec_b1 = (const float*)d_in[7];
  const float* dec_w2 = (const float*)d_in[8];
  const float* dec_b2 = (const float*)d_in[9];

  float* out = (float*)d_out;
  float* ws  = (float*)d_ws;

  float* bands_hat = out + OUT_BH;
  float* z_e       = out + OUT_ZE;
  float* z_q       = out + OUT_ZQ;
  float* idx_f     = out + OUT_IDX;
  float* loss_out  = out + OUT_LOSS;

  float* H        = ws + WS_H;
  float* cn       = ws + WS_CN;
  float* loss_acc = ws + WS_LOSS;
  unsigned short* h2bf = (unsigned short*)(ws + WS_H2BF_F);
  unsigned short* zqb  = (unsigned short*)(ws + WS_ZQB_F);
  unsigned short* w1b  = (unsigned short*)(ws + WS_W1B_F);
  unsigned short* w2b  = (unsigned short*)(ws + WS_W2B_F);

  cn_kernel<<<dim3((GQ * KQ + 255) / 256), dim3(256), 0, stream>>>(cbooks, cn, loss_acc);

  // Encoder (fp32): H = relu(bands@W1+b1); z_e = H@W2+b2  (round-5 configs)
  gemm_f32<128, 8, 8, true ><<<dim3(HIDDEN / 128, NROWS / 128), dim3(256), 0, stream>>>(
      bands, enc_w1, enc_b1, H, NROWS, HIDDEN, NBANDS);
  gemm_f32<64, 4, 8, false><<<dim3(LATENT / 64, NROWS / 128), dim3(256), 0, stream>>>(
      H, enc_w2, enc_b2, z_e, NROWS, LATENT, HIDDEN);

  // Decoder weights -> bf16
  wconv_kernel<<<dim3((LATENT * HIDDEN + HIDDEN * NBANDS + 255) / 256), dim3(256), 0, stream>>>(
      dec_w1, dec_w2, w1b, w2b);

  // VQ (fp32 exact; also emits bf16 z_q)
  vq_kernel<<<dim3(NROWS / VQ_ROWS, GQ), dim3(256), 0, stream>>>(
      z_e, cbooks, cn, z_q, zqb, idx_f, loss_acc);

  // Decoder (bf16 MFMA)
  gemm_bf16_mfma<32, true ><<<dim3(HIDDEN / 64, NROWS / 128), dim3(256), 0, stream>>>(
      zqb, w1b, dec_b1, (void*)h2bf, NROWS, HIDDEN, LATENT);
  gemm_bf16_mfma<16, false><<<dim3(NBANDS / 64, NROWS / 64), dim3(256), 0, stream>>>(
      h2bf, w2b, dec_b2, (void*)bands_hat, NROWS, NBANDS, HIDDEN);

  loss_kernel<<<1, 1, 0, stream>>>(loss_acc, loss_out);
}

// Round 11
// 317.829 us; speedup vs baseline: 2.4343x; 1.0112x over previous
//
#include <hip/hip_runtime.h>

// Problem constants
#define NBANDS 64
#define LATENT 256
#define HIDDEN 512
#define GQ 8
#define KQ 1024
#define GD 32
#define NROWS 16000   // B*T = 16*1000

// d_out float offsets
#define OUT_BH   0
#define OUT_ZE   1024000
#define OUT_ZQ   5120000
#define OUT_IDX  9216000
#define OUT_LOSS 9344000

// ws float offsets.  H region [0,8192000) is live ONLY between enc1 and enc2;
// bf16 buffers overlay it and MUST be written after enc2 (r10's NaN bug was
// violating exactly this).
#define WS_H     0
#define WS_H2BF_F  0
#define WS_ZQB_F   4096000
#define WS_W1B_F   6144000
#define WS_W2B_F   6209536
#define WS_CN    8192000
#define WS_LOSS  8200192

typedef __attribute__((ext_vector_type(8))) short bf16x8;
typedef __attribute__((ext_vector_type(4))) float f32x4;

__device__ __forceinline__ unsigned short f2bf(float f) {
  unsigned u = __builtin_bit_cast(unsigned, f);
  unsigned r = u + 0x7FFFu + ((u >> 16) & 1u);   // RNE; inputs finite
  return (unsigned short)(r >> 16);
}

// async 16B global->LDS DMA (gfx950; LDS dst is wave-uniform base + lane*16)
__device__ __forceinline__ void g2l16(const float* g, float* l) {
  __builtin_amdgcn_global_load_lds(
      (const __attribute__((address_space(1))) unsigned int*)g,
      (__attribute__((address_space(3))) unsigned int*)l, 16, 0, 0);
}

// ---------------------------------------------------------------------------
// fp32 GEMM, 128xBN tile, TMxTN microtile, templated BK, 256 threads.
// Ascending-k accumulation regardless of BK -> bit-identical results.
// ---------------------------------------------------------------------------
template<int BN, int TM, int TN, int BK, bool RELU>
__global__ __launch_bounds__(256) void gemm_f32(
    const float* __restrict__ A, const float* __restrict__ B,
    const float* __restrict__ bias, float* __restrict__ C,
    int M, int N, int K) {
  constexpr int BM = 128;
  constexpr int NTX = BN / TN;
  constexpr int AF4 = BK / 8;
  constexpr int QPR = BN / 4;
  constexpr int BF4 = BK * BN / 1024;

  __shared__ float As[BK][BM + 8];
  __shared__ float Bs[BK][BN + 4];

  const int tid = threadIdx.x;
  const int tx = tid % NTX;
  const int ty = tid / NTX;
  const int row0 = blockIdx.y * BM;
  const int col0 = blockIdx.x * BN;

  const int arow = tid >> 1;
  const int akq  = (tid & 1) * (BK / 2);

  float acc[TM][TN] = {};

  for (int k0 = 0; k0 < K; k0 += BK) {
    float4 av[AF4], bv[BF4];
#pragma unroll
    for (int q = 0; q < AF4; ++q)
      av[q] = *reinterpret_cast<const float4*>(
          &A[(size_t)(row0 + arow) * K + k0 + akq + q * 4]);
#pragma unroll
    for (int t = 0; t < BF4; ++t) {
      const int qq = tid * BF4 + t;
      const int bk = qq / QPR, bn4 = qq % QPR;
      bv[t] = *reinterpret_cast<const float4*>(
          &B[(size_t)(k0 + bk) * N + col0 + bn4 * 4]);
    }
    __syncthreads();
#pragma unroll
    for (int q = 0; q < AF4; ++q) {
      As[akq + q * 4 + 0][arow] = av[q].x;
      As[akq + q * 4 + 1][arow] = av[q].y;
      As[akq + q * 4 + 2][arow] = av[q].z;
      As[akq + q * 4 + 3][arow] = av[q].w;
    }
#pragma unroll
    for (int t = 0; t < BF4; ++t) {
      const int qq = tid * BF4 + t;
      const int bk = qq / QPR, bn4 = qq % QPR;
      *reinterpret_cast<float4*>(&Bs[bk][bn4 * 4]) = bv[t];
    }
    __syncthreads();

#pragma unroll
    for (int kk = 0; kk < BK; ++kk) {
      float a[TM], b[TN];
#pragma unroll
      for (int q = 0; q < TM / 4; ++q) {
        float4 v = *reinterpret_cast<const float4*>(&As[kk][ty * TM + q * 4]);
        a[q * 4 + 0] = v.x; a[q * 4 + 1] = v.y;
        a[q * 4 + 2] = v.z; a[q * 4 + 3] = v.w;
      }
#pragma unroll
      for (int q = 0; q < TN / 4; ++q) {
        float4 v = *reinterpret_cast<const float4*>(&Bs[kk][tx * TN + q * 4]);
        b[q * 4 + 0] = v.x; b[q * 4 + 1] = v.y;
        b[q * 4 + 2] = v.z; b[q * 4 + 3] = v.w;
      }
#pragma unroll
      for (int i = 0; i < TM; ++i)
#pragma unroll
        for (int j = 0; j < TN; ++j)
          acc[i][j] = fmaf(a[i], b[j], acc[i][j]);
    }
  }

  float bb[TN];
#pragma unroll
  for (int q = 0; q < TN / 4; ++q) {
    float4 v = *reinterpret_cast<const float4*>(&bias[col0 + tx * TN + q * 4]);
    bb[q * 4 + 0] = v.x; bb[q * 4 + 1] = v.y;
    bb[q * 4 + 2] = v.z; bb[q * 4 + 3] = v.w;
  }
#pragma unroll
  for (int i = 0; i < TM; ++i) {
    const int r = row0 + ty * TM + i;
#pragma unroll
    for (int q = 0; q < TN / 4; ++q) {
      float4 v;
      float* vp = &v.x;
#pragma unroll
      for (int j = 0; j < 4; ++j) {
        float t = acc[i][q * 4 + j] + bb[q * 4 + j];
        if (RELU) t = fmaxf(t, 0.0f);
        vp[j] = t;
      }
      *reinterpret_cast<float4*>(&C[(size_t)r * N + col0 + tx * TN + q * 4]) = v;
    }
  }
}

// ---------------------------------------------------------------------------
// bf16 MFMA GEMM with TRANSPOSED B (BT[n][k]) -> b128 B-staging.
// DO_LOSS: block(0,0) tid0 finalizes the vq loss scalar.
// ---------------------------------------------------------------------------
template<int WM, bool OUT_BF16, bool DO_LOSS>
__global__ __launch_bounds__(256) void gemm_bf16_mfma(
    const unsigned short* __restrict__ A, const unsigned short* __restrict__ BT,
    const float* __restrict__ bias, void* __restrict__ Cout,
    int M, int N, int K,
    const float* __restrict__ loss_acc, float* __restrict__ loss_out) {
  constexpr int BM = 4 * WM;
  constexpr int MT = WM / 16;

  __shared__ unsigned short As[BM][40];
  __shared__ unsigned short Bs[64][40];

  const int tid  = threadIdx.x;
  const int wave = tid >> 6;
  const int lane = tid & 63;
  const int quad = lane >> 4;
  const int l16  = lane & 15;
  const int row0 = blockIdx.y * BM;
  const int col0 = blockIdx.x * 64;

  if (DO_LOSS && blockIdx.x == 0 && blockIdx.y == 0 && tid == 0)
    loss_out[0] = 0.5f * loss_acc[0] / (float)((size_t)NROWS * GD);

  f32x4 acc[MT][4];
#pragma unroll
  for (int mt = 0; mt < MT; ++mt)
#pragma unroll
    for (int nt = 0; nt < 4; ++nt) acc[mt][nt] = (f32x4){0.f, 0.f, 0.f, 0.f};

  for (int k0 = 0; k0 < K; k0 += 32) {
    __syncthreads();
    if constexpr (BM == 128) {
      const int r = tid >> 1, seg = (tid & 1) * 16;
      const uint4* src = reinterpret_cast<const uint4*>(
          &A[(size_t)(row0 + r) * K + k0 + seg]);
      uint4* dst = reinterpret_cast<uint4*>(&As[r][seg]);
      dst[0] = src[0]; dst[1] = src[1];
    } else {
      const int r = tid >> 2, seg = (tid & 3) * 8;
      *reinterpret_cast<uint4*>(&As[r][seg]) =
          *reinterpret_cast<const uint4*>(&A[(size_t)(row0 + r) * K + k0 + seg]);
    }
    {
      const int n = tid >> 2, kc = (tid & 3) * 8;
      *reinterpret_cast<uint4*>(&Bs[n][kc]) =
          *reinterpret_cast<const uint4*>(&BT[(size_t)(col0 + n) * K + k0 + kc]);
    }
    __syncthreads();

    bf16x8 af[MT], bf[4];
#pragma unroll
    for (int mt = 0; mt < MT; ++mt)
      af[mt] = *reinterpret_cast<const bf16x8*>(
          &As[wave * WM + mt * 16 + l16][quad * 8]);
#pragma unroll
    for (int nt = 0; nt < 4; ++nt)
      bf[nt] = *reinterpret_cast<const bf16x8*>(&Bs[nt * 16 + l16][quad * 8]);
#pragma unroll
    for (int mt = 0; mt < MT; ++mt)
#pragma unroll
      for (int nt = 0; nt < 4; ++nt)
        acc[mt][nt] = __builtin_amdgcn_mfma_f32_16x16x32_bf16(
            af[mt], bf[nt], acc[mt][nt], 0, 0, 0);
  }

#pragma unroll
  for (int mt = 0; mt < MT; ++mt)
#pragma unroll
    for (int nt = 0; nt < 4; ++nt) {
      const int col = col0 + nt * 16 + l16;
      const float bv = bias[col];
#pragma unroll
      for (int r = 0; r < 4; ++r) {
        const int grow = row0 + wave * WM + mt * 16 + quad * 4 + r;
        float v = acc[mt][nt][r] + bv;
        if constexpr (OUT_BF16) {
          v = fmaxf(v, 0.0f);
          ((unsigned short*)Cout)[(size_t)grow * N + col] = f2bf(v);
        } else {
          ((float*)Cout)[(size_t)grow * N + col] = v;
        }
      }
    }
}

// ---------------------------------------------------------------------------
// prep_cn: cn = ||codebook||^2 + zero loss accumulator.  Runs FIRST.
// ---------------------------------------------------------------------------
__global__ void prep_cn(const float* __restrict__ cb, float* __restrict__ cn,
                        float* __restrict__ loss_acc) {
  const int i = blockIdx.x * 256 + threadIdx.x;
  if (i == 0) loss_acc[0] = 0.0f;
  if (i < GQ * KQ) {
    const float* c = cb + (size_t)i * GD;
    float s = 0.0f;
#pragma unroll
    for (int d = 0; d < GD; ++d) s = fmaf(c[d], c[d], s);
    cn[i] = s;
  }
}

// ---------------------------------------------------------------------------
// prep_wT: decoder weights -> TRANSPOSED bf16 (w1bT[n*256+k], w2bT[n*512+k]).
// MUST run after enc2 (w1bT/w2bT overlay the then-dead fp32 H region).
// ---------------------------------------------------------------------------
__global__ void prep_wT(const float* __restrict__ w1, const float* __restrict__ w2,
                        unsigned short* __restrict__ w1bT,
                        unsigned short* __restrict__ w2bT) {
  const int t = blockIdx.x * 256 + threadIdx.x;
  if (t < 16384) {                       // w1: [256 k][512 n] -> w1bT[n][k]
    const int n = t >> 5, k0 = (t & 31) * 8;
    alignas(16) unsigned short o[8];
#pragma unroll
    for (int q = 0; q < 8; ++q) o[q] = f2bf(w1[(size_t)(k0 + q) * HIDDEN + n]);
    *reinterpret_cast<uint4*>(&w1bT[(size_t)n * LATENT + k0]) =
        *reinterpret_cast<const uint4*>(o);
  } else if (t < 20480) {                // w2: [512 k][64 n] -> w2bT[n][k]
    const int u = t - 16384;
    const int n = u >> 6, k0 = (u & 63) * 8;
    alignas(16) unsigned short o[8];
#pragma unroll
    for (int q = 0; q < 8; ++q) o[q] = f2bf(w2[(size_t)(k0 + q) * NBANDS + n]);
    *reinterpret_cast<uint4*>(&w2bT[(size_t)n * HIDDEN + k0]) =
        *reinterpret_cast<const uint4*>(o);
  }
}

// ---------------------------------------------------------------------------
// VQ (unchanged from round 9: LDS-B, async dbuf DMA, XOR swizzles)
// ---------------------------------------------------------------------------
#define VQ_ROWS 128
#define VQ_CHUNK 128
#define VQ_NCHUNK (KQ / VQ_CHUNK)   // 8
#define ZPAD 36

__global__ __launch_bounds__(256) void vq_kernel(
    const float* __restrict__ z_e, const float* __restrict__ cb,
    const float* __restrict__ cn, float* __restrict__ z_q,
    unsigned short* __restrict__ zqb,
    float* __restrict__ idx_out, float* __restrict__ loss_acc) {
  const int g    = blockIdx.y;
  const int row0 = blockIdx.x * VQ_ROWS;
  const int tid  = threadIdx.x;
  const int tx   = tid & 15;
  const int ty   = tid >> 4;

  __shared__ float smem[VQ_ROWS * ZPAD + 2 * VQ_CHUNK * GD];  // 51200 B
  float* zs  = smem;
  float* cbF = smem + VQ_ROWS * ZPAD;

  const float* cbg = cb + (size_t)g * KQ * GD;
  const float* cng = cn + (size_t)g * KQ;

  {
    const float* src = cbg;
    float* dst = cbF;
#pragma unroll
    for (int q4 = 0; q4 < 4; ++q4) {
      const int s = q4 * 256 + tid;
      const int r = s >> 3;
      const int q = (s & 7) ^ (r & 7);
      g2l16(src + r * GD + q * 4, dst + s * 4);
    }
  }

  {
    const int r   = tid >> 1;
    const int off = (tid & 1) << 4;
    const int key = ((r >> 3) & 3) << 2;
    const float4* src = reinterpret_cast<const float4*>(
        &z_e[(size_t)(row0 + r) * LATENT + g * GD + off]);
#pragma unroll
    for (int q = 0; q < 4; ++q)
      *reinterpret_cast<float4*>(&zs[r * ZPAD + ((off + q * 4) ^ key)]) = src[q];
  }

  const int akey = (ty & 3) << 2;
  const int bkey = tx & 7;

  float best[8];
  int   bidx[8];
#pragma unroll
  for (int i = 0; i < 8; ++i) { best[i] = 3.0e38f; bidx[i] = 0; }

  for (int ch = 0; ch < VQ_NCHUNK; ++ch) {
    __syncthreads();

    if (ch + 1 < VQ_NCHUNK) {
      const float* src = cbg + (size_t)(ch + 1) * VQ_CHUNK * GD;
      float* dst = cbF + ((ch + 1) & 1) * (VQ_CHUNK * GD);
#pragma unroll
      for (int q4 = 0; q4 < 4; ++q4) {
        const int s = q4 * 256 + tid;
        const int r = s >> 3;
        const int q = (s & 7) ^ (r & 7);
        g2l16(src + r * GD + q * 4, dst + s * 4);
      }
    }

    const float* cbuf = cbF + (ch & 1) * (VQ_CHUNK * GD);

    float acc[8][8];
#pragma unroll
    for (int i = 0; i < 8; ++i)
#pragma unroll
      for (int j = 0; j < 8; ++j) acc[i][j] = 0.0f;

#pragma unroll 2
    for (int d0 = 0; d0 < GD; d0 += 4) {
      float4 a[8], b[8];
#pragma unroll
      for (int s = 0; s < 8; ++s)
        a[s] = *reinterpret_cast<const float4*>(
            &zs[(ty * 8 + s) * ZPAD + (d0 ^ akey)]);
      const int bq = ((d0 >> 2) ^ bkey) << 2;
#pragma unroll
      for (int j = 0; j < 8; ++j)
        b[j] = *reinterpret_cast<const float4*>(
            &cbuf[(j * 16 + tx) * GD + bq]);
#pragma unroll
      for (int i = 0; i < 8; ++i)
#pragma unroll
        for (int j = 0; j < 8; ++j) {
          float t = acc[i][j];
          t = fmaf(a[i].x, b[j].x, t);
          t = fmaf(a[i].y, b[j].y, t);
          t = fmaf(a[i].z, b[j].z, t);
          t = fmaf(a[i].w, b[j].w, t);
          acc[i][j] = t;
        }
    }

#pragma unroll
    for (int j = 0; j < 8; ++j) {
      const int k = ch * VQ_CHUNK + j * 16 + tx;
      const float cnv = cng[k];
#pragma unroll
      for (int i = 0; i < 8; ++i) {
        const float dist = fmaf(-2.0f, acc[i][j], cnv);
        if (dist < best[i]) { best[i] = dist; bidx[i] = k; }
      }
    }
  }

  __syncthreads();
  float* m_d = cbF;
  int*   m_i = reinterpret_cast<int*>(cbF + 16 * 129);
  float* red = cbF + 2 * 16 * 129 + 32;
#pragma unroll
  for (int i = 0; i < 8; ++i) {
    m_d[tx * 129 + ty * 8 + i] = best[i];
    m_i[tx * 129 + ty * 8 + i] = bidx[i];
  }
  __syncthreads();

  float sse_part = 0.0f;
  if (tid < VQ_ROWS) {
    const int row = tid;
    const int rkey = ((row >> 3) & 3) << 2;
    float mb = m_d[row];
    int   mi = m_i[row];
#pragma unroll
    for (int t = 1; t < 16; ++t) {
      const float v = m_d[t * 129 + row];
      const int  ix = m_i[t * 129 + row];
      if (v < mb || (v == mb && ix < mi)) { mb = v; mi = ix; }
    }

    const float* c = cbg + (size_t)mi * GD;
    float cw[GD];
#pragma unroll
    for (int q = 0; q < 8; ++q) {
      float4 v = *reinterpret_cast<const float4*>(&c[q * 4]);
      cw[q * 4 + 0] = v.x; cw[q * 4 + 1] = v.y;
      cw[q * 4 + 2] = v.z; cw[q * 4 + 3] = v.w;
    }
    float sse = 0.0f;
#pragma unroll
    for (int d = 0; d < GD; ++d) {
      const float diff = cw[d] - zs[row * ZPAD + (d ^ rkey)];
      sse = fmaf(diff, diff, sse);
    }
    float4* zq = reinterpret_cast<float4*>(
        &z_q[(size_t)(row0 + row) * LATENT + g * GD]);
#pragma unroll
    for (int q = 0; q < 8; ++q)
      zq[q] = make_float4(cw[q * 4], cw[q * 4 + 1], cw[q * 4 + 2], cw[q * 4 + 3]);

    alignas(16) unsigned short zb[GD];
#pragma unroll
    for (int d = 0; d < GD; ++d) zb[d] = f2bf(cw[d]);
    uint4* dstb = reinterpret_cast<uint4*>(
        zqb + (size_t)(row0 + row) * LATENT + g * GD);
    const uint4* srcb = reinterpret_cast<const uint4*>(zb);
#pragma unroll
    for (int q = 0; q < 4; ++q) dstb[q] = srcb[q];

    idx_out[(size_t)(row0 + row) * GQ + g] = (float)mi;
    sse_part = sse;
  }

  if (tid < VQ_ROWS) red[tid] = sse_part;
  __syncthreads();
  if (tid < 64) {
    float s = red[tid] + red[tid + 64];
#pragma unroll
    for (int off = 32; off > 0; off >>= 1)
      s += __shfl_down(s, off, 64);
    if (tid == 0) atomicAdd(loss_acc, s);
  }
}

// ---------------------------------------------------------------------------
extern "C" void kernel_launch(void* const* d_in, const int* in_sizes, int n_in,
                              void* d_out, int out_size, void* d_ws, size_t ws_size,
                              hipStream_t stream) {
  const float* bands  = (const float*)d_in[0];
  const float* enc_w1 = (const float*)d_in[1];
  const float* enc_b1 = (const float*)d_in[2];
  const float* enc_w2 = (const float*)d_in[3];
  const float* enc_b2 = (const float*)d_in[4];
  const float* cbooks = (const float*)d_in[5];
  const float* dec_w1 = (const float*)d_in[6];
  const float* dec_b1 = (const float*)d_in[7];
  const float* dec_w2 = (const float*)d_in[8];
  const float* dec_b2 = (const float*)d_in[9];

  float* out = (float*)d_out;
  float* ws  = (float*)d_ws;

  float* bands_hat = out + OUT_BH;
  float* z_e       = out + OUT_ZE;
  float* z_q       = out + OUT_ZQ;
  float* idx_f     = out + OUT_IDX;
  float* loss_out  = out + OUT_LOSS;

  float* H        = ws + WS_H;
  float* cn       = ws + WS_CN;
  float* loss_acc = ws + WS_LOSS;
  unsigned short* h2bf = (unsigned short*)(ws + WS_H2BF_F);
  unsigned short* zqb  = (unsigned short*)(ws + WS_ZQB_F);
  unsigned short* w1bT = (unsigned short*)(ws + WS_W1B_F);
  unsigned short* w2bT = (unsigned short*)(ws + WS_W2B_F);

  // cn + loss zero (safe: outside H region)
  prep_cn<<<dim3(32), dim3(256), 0, stream>>>(cbooks, cn, loss_acc);

  // Encoder (fp32): H = relu(bands@W1+b1); z_e = H@W2+b2 (enc2 BK=32)
  gemm_f32<128, 8, 8, 16, true ><<<dim3(HIDDEN / 128, NROWS / 128), dim3(256), 0, stream>>>(
      bands, enc_w1, enc_b1, H, NROWS, HIDDEN, NBANDS);
  gemm_f32<64, 4, 8, 32, false><<<dim3(LATENT / 64, NROWS / 128), dim3(256), 0, stream>>>(
      H, enc_w2, enc_b2, z_e, NROWS, LATENT, HIDDEN);

  // Decoder weights -> transposed bf16 (H is dead now; overlay is safe)
  prep_wT<<<dim3(80), dim3(256), 0, stream>>>(dec_w1, dec_w2, w1bT, w2bT);

  // VQ (fp32 exact; also emits bf16 z_q)
  vq_kernel<<<dim3(NROWS / VQ_ROWS, GQ), dim3(256), 0, stream>>>(
      z_e, cbooks, cn, z_q, zqb, idx_f, loss_acc);

  // Decoder (bf16 MFMA, transposed-weight staging); dec1 finalizes loss
  gemm_bf16_mfma<32, true, true ><<<dim3(HIDDEN / 64, NROWS / 128), dim3(256), 0, stream>>>(
      zqb, w1bT, dec_b1, (void*)h2bf, NROWS, HIDDEN, LATENT, loss_acc, loss_out);
  gemm_bf16_mfma<16, false, false><<<dim3(NBANDS / 64, NROWS / 64), dim3(256), 0, stream>>>(
      h2bf, w2bT, dec_b2, (void*)bands_hat, NROWS, NBANDS, HIDDEN, loss_acc, loss_out);
}